// Round 2
// baseline (31582.968 us; speedup 1.0000x reference)
//
#include <hip/hip_runtime.h>

typedef unsigned short u16;
typedef __attribute__((ext_vector_type(8))) short bh8;
typedef __attribute__((ext_vector_type(4))) float f4;

#define GRID_BLOCKS 256
#define THREADS 256

__device__ __forceinline__ u16 f2b(float f) {
  unsigned u = __float_as_uint(f);
  return (u16)((u + 0x7FFFu + ((u >> 16) & 1u)) >> 16);
}
__device__ __forceinline__ float elu_f(float x) { return x > 0.f ? x : __expf(x) - 1.f; }
__device__ __forceinline__ float sigm_f(float x) { return 1.f / (1.f + __expf(-x)); }
__device__ __forceinline__ float softplus_f(float x) { return x > 20.f ? x : log1pf(__expf(x)); }

// Device-scope software grid barrier (monotonic counter; bar zeroed by
// hipMemsetAsync before launch). Safe because grid(256) <= guaranteed
// co-residency: __launch_bounds__(256,2) -> 2 blocks/CU * 256 CUs = 512.
__device__ __forceinline__ void gbar(int* bar, int target) {
  __syncthreads();
  if (threadIdx.x == 0) {
    __threadfence();  // release: make our writes visible device-wide
    __hip_atomic_fetch_add(bar, 1, __ATOMIC_RELEASE, __HIP_MEMORY_SCOPE_AGENT);
    while (__hip_atomic_load(bar, __ATOMIC_ACQUIRE, __HIP_MEMORY_SCOPE_AGENT) < target)
      __builtin_amdgcn_s_sleep(1);
    __threadfence();  // acquire: invalidate stale cached lines
  }
  __syncthreads();
}

struct RArgs {
  const float* actions; const float* nont; const float* obs; const float* noise;
  const float* init_stoc; const float* init_deter;
  const float* W_in; const float* b_in; const float* W_ih; const float* W_hh;
  const float* b_ih; const float* b_hh;
  const float* Wp1; const float* bp1; const float* Wp2; const float* bp2;
  const float* Wq1; const float* bq1; const float* Wq2; const float* bq2;
  float* out;
  u16 *Wi_b, *Wih_b, *Whh_b, *Wp1_b, *Wp2_b, *Wq1_b, *Wq2_b;
  u16 *xin, *x_b, *hprev_b, *hb, *obs_cur, *g1, *q1e;
  float *h32, *gg;
  int* bar;
};

// C[64x128] = A[64xK] * B^T[128xK], bf16 in, fp32 acc.
// A can switch source at k==kSplit (for concat([h, obs]) K=2048).
__device__ __forceinline__ void gemm_tile_64x128(
    const u16* A0, const u16* A1, int kSplit,
    long lda, const u16* Bw, long ldb, int K, int m0,
    char* sm, f4 acc[2][4])
{
  u16* sA = (u16*)sm;            // [64][64]
  u16* sB = (u16*)(sm + 8192);   // [128][64]
  const int tid = threadIdx.x;
  const int l = tid & 63, w = tid >> 6;
  const int wrow = (w & 1) * 32, wcol = (w >> 1) * 64;
  const int am = l & 15, ak = (l >> 4) * 8;
  const int arow = tid >> 2, acol = (tid & 3) * 16;
  const int brow = tid >> 1, bcol = (tid & 1) * 32;
  const f4 z4 = {0.f, 0.f, 0.f, 0.f};
#pragma unroll
  for (int i = 0; i < 2; ++i)
#pragma unroll
    for (int j = 0; j < 4; ++j) acc[i][j] = z4;

  for (int k0 = 0; k0 < K; k0 += 64) {
    const u16* Ab; int ka;
    if (k0 < kSplit) { Ab = A0; ka = k0; } else { Ab = A1; ka = k0 - kSplit; }
    __syncthreads();
    {
      const u16* src = Ab + (long)(m0 + arow) * lda + ka + acol;
      *(bh8*)(sA + tid * 16)     = *(const bh8*)(src);
      *(bh8*)(sA + tid * 16 + 8) = *(const bh8*)(src + 8);
    }
    {
      const u16* src = Bw + (long)brow * ldb + k0 + bcol;
      u16* d = sB + tid * 32;
      *(bh8*)(d)      = *(const bh8*)(src);
      *(bh8*)(d + 8)  = *(const bh8*)(src + 8);
      *(bh8*)(d + 16) = *(const bh8*)(src + 16);
      *(bh8*)(d + 24) = *(const bh8*)(src + 24);
    }
    __syncthreads();
#pragma unroll
    for (int kc = 0; kc < 64; kc += 32) {
      bh8 a0 = *(bh8*)(sA + (wrow + am) * 64 + kc + ak);
      bh8 a1 = *(bh8*)(sA + (wrow + 16 + am) * 64 + kc + ak);
#pragma unroll
      for (int j = 0; j < 4; ++j) {
        bh8 bv = *(bh8*)(sB + (wcol + j * 16 + am) * 64 + kc + ak);
        acc[0][j] = __builtin_amdgcn_mfma_f32_16x16x32_bf16(a0, bv, acc[0][j], 0, 0, 0);
        acc[1][j] = __builtin_amdgcn_mfma_f32_16x16x32_bf16(a1, bv, acc[1][j], 0, 0, 0);
      }
    }
  }
  __syncthreads();
}

__global__ __launch_bounds__(THREADS, 2) void rssm_kernel(RArgs a) {
  __shared__ __align__(16) char sm[34816];
  const int tid = threadIdx.x;
  const int bid = blockIdx.x;
  const long gsz = (long)GRID_BLOCKS * THREADS;
  const long g0 = (long)bid * THREADS + tid;
  const int l = tid & 63, w = tid >> 6;
  const int dr = (l >> 4) * 4, dc = l & 15;
  const int wrow = (w & 1) * 32, wcol = (w >> 1) * 64;
  int round = 0;

  // ---- init / weight conversion (every call: ws is re-poisoned) ----
  for (long i = g0; i < 3072 * 1024; i += gsz) { a.Wih_b[i] = f2b(a.W_ih[i]); a.Whh_b[i] = f2b(a.W_hh[i]); }
  for (long i = g0; i < 1024 * 2048; i += gsz) a.Wq1_b[i] = f2b(a.Wq1[i]);
  for (long i = g0; i < 1024 * 1024; i += gsz) a.Wp1_b[i] = f2b(a.Wp1[i]);
  for (long i = g0; i < 256 * 1024; i += gsz) { a.Wp2_b[i] = f2b(a.Wp2[i]); a.Wq2_b[i] = f2b(a.Wq2[i]); }
  for (long i = g0; i < 1024 * 192; i += gsz) {
    long n = i / 192, k = i - n * 192;
    a.Wi_b[i] = (k < 144) ? f2b(a.W_in[n * 144 + k]) : (u16)0;
  }
  for (long i = g0; i < 512 * 1024; i += gsz) a.h32[i] = a.init_deter[i];
  for (long i = g0; i < 512 * 192; i += gsz) {
    long b = i / 192, k = i - b * 192;
    float v = 0.f;
    if (k < 128) v = a.init_stoc[b * 128 + k] * a.nont[b];
    else if (k < 144) v = a.actions[b * 16 + (k - 128)];
    a.xin[i] = f2b(v);
  }
  round += GRID_BLOCKS; gbar(a.bar, round);

  for (int t = 0; t < 64; ++t) {
    // ---- Stage A: x = elu([stoc*nt ; a] @ W_in^T + b_in)  + side converts ----
    if (bid < 64) {
      const int m0 = (bid >> 3) * 64, n0 = (bid & 7) * 128;
      f4 acc[2][4];
      gemm_tile_64x128(a.xin, nullptr, 1 << 30, 192, a.Wi_b + (long)n0 * 192, 192, 192, m0, sm, acc);
#pragma unroll
      for (int i = 0; i < 2; ++i)
#pragma unroll
        for (int j = 0; j < 4; ++j)
#pragma unroll
          for (int r = 0; r < 4; ++r) {
            int row = m0 + wrow + i * 16 + dr + r;
            int col = n0 + wcol + j * 16 + dc;
            a.x_b[(long)row * 1024 + col] = f2b(elu_f(acc[i][j][r] + a.b_in[col]));
          }
    } else if (bid < 128) {
      const int base = (bid - 64) * 8192;
      for (int i = tid; i < 8192; i += THREADS) {
        int idx = base + i, b = idx >> 10;
        a.hprev_b[idx] = f2b(a.h32[idx] * a.nont[t * 512 + b]);
      }
    } else if (bid < 192) {
      const int base = (bid - 128) * 8192;
      const float* op = a.obs + (long)t * 512 * 1024;
      for (int i = tid; i < 8192; i += THREADS)
        a.obs_cur[base + i] = f2b(op[base + i]);
    }
    round += GRID_BLOCKS; gbar(a.bar, round);

    // ---- Stage B: gi = x @ W_ih^T ; gh = (h_prev*nt) @ W_hh^T  (raw, fp32) ----
    for (int tile = bid; tile < 384; tile += GRID_BLOCKS) {
      const int tm = tile / 48, tn = tile - tm * 48;
      const int m0 = tm * 64; const long n0 = (long)tn * 128;
      const u16* Aq; const u16* Bq;
      if (n0 < 3072) { Aq = a.x_b;     Bq = a.Wih_b + n0 * 1024; }
      else           { Aq = a.hprev_b; Bq = a.Whh_b + (n0 - 3072) * 1024; }
      f4 acc[2][4];
      gemm_tile_64x128(Aq, nullptr, 1 << 30, 1024, Bq, 1024, 1024, m0, sm, acc);
#pragma unroll
      for (int i = 0; i < 2; ++i)
#pragma unroll
        for (int j = 0; j < 4; ++j)
#pragma unroll
          for (int r = 0; r < 4; ++r) {
            int row = m0 + wrow + i * 16 + dr + r;
            long col = n0 + wcol + j * 16 + dc;
            a.gg[(long)row * 6144 + col] = acc[i][j][r];
          }
    }
    round += GRID_BLOCKS; gbar(a.bar, round);

    // ---- Stage C: GRU combine (elementwise, fp32 state) ----
    for (long idx = g0; idx < 512 * 1024; idx += gsz) {
      int b = (int)(idx >> 10), c = (int)(idx & 1023);
      const float* g = a.gg + (long)b * 6144;
      float r = sigm_f(g[c]        + a.b_ih[c]        + g[3072 + c] + a.b_hh[c]);
      float z = sigm_f(g[1024 + c] + a.b_ih[1024 + c] + g[4096 + c] + a.b_hh[1024 + c]);
      float n = tanhf (g[2048 + c] + a.b_ih[2048 + c] + r * (g[5120 + c] + a.b_hh[2048 + c]));
      float hp = a.h32[idx] * a.nont[t * 512 + b];
      float h = (1.f - z) * n + z * hp;
      a.h32[idx] = h;
      a.hb[idx] = f2b(h);
      a.out[((long)t * 512 + b) * 1536 + 512 + c] = h;
    }
    round += GRID_BLOCKS; gbar(a.bar, round);

    // ---- Stage D: p1 = elu(h@Wp1^T+bp1) ; q1 = elu([h;obs]@Wq1^T+bq1) ----
    if (bid < 128) {
      f4 acc[2][4];
      if (bid < 64) {
        const int m0 = (bid >> 3) * 64, n0 = (bid & 7) * 128;
        gemm_tile_64x128(a.hb, nullptr, 1 << 30, 1024, a.Wp1_b + (long)n0 * 1024, 1024, 1024, m0, sm, acc);
#pragma unroll
        for (int i = 0; i < 2; ++i)
#pragma unroll
          for (int j = 0; j < 4; ++j)
#pragma unroll
            for (int r = 0; r < 4; ++r) {
              int row = m0 + wrow + i * 16 + dr + r;
              int col = n0 + wcol + j * 16 + dc;
              a.g1[(long)row * 1024 + col] = f2b(elu_f(acc[i][j][r] + a.bp1[col]));
            }
      } else {
        const int u = bid - 64;
        const int m0 = (u >> 3) * 64, n0 = (u & 7) * 128;
        gemm_tile_64x128(a.hb, a.obs_cur, 1024, 1024, a.Wq1_b + (long)n0 * 2048, 2048, 2048, m0, sm, acc);
#pragma unroll
        for (int i = 0; i < 2; ++i)
#pragma unroll
          for (int j = 0; j < 4; ++j)
#pragma unroll
            for (int r = 0; r < 4; ++r) {
              int row = m0 + wrow + i * 16 + dr + r;
              int col = n0 + wcol + j * 16 + dc;
              a.q1e[(long)row * 1024 + col] = f2b(elu_f(acc[i][j][r] + a.bq1[col]));
            }
      }
    }
    round += GRID_BLOCKS; gbar(a.bar, round);

    // ---- Stage E: p2/q2 (16x256 tiles, K=1024) + sample + outputs + next xin ----
    if (bid < 64) {
      const bool isQ = bid >= 32;
      const int m0 = (bid & 31) * 16;
      const u16* Aq = isQ ? a.q1e : a.g1;
      const u16* Bq = isQ ? a.Wq2_b : a.Wp2_b;
      const float* bias = isQ ? a.bq2 : a.bp2;
      u16* sA = (u16*)sm;            // [16][64]
      u16* sB = (u16*)(sm + 2048);   // [256][64]
      const f4 z4 = {0.f, 0.f, 0.f, 0.f};
      f4 acc[4];
#pragma unroll
      for (int j = 0; j < 4; ++j) acc[j] = z4;
      const int am = l & 15, ak = (l >> 4) * 8;
      for (int k0 = 0; k0 < 1024; k0 += 64) {
        __syncthreads();
        {
          int f = tid * 4;
          const u16* src = Aq + (long)(m0 + (f >> 6)) * 1024 + k0 + (f & 63);
          *(unsigned long long*)(sA + f) = *(const unsigned long long*)src;
        }
#pragma unroll
        for (int i = 0; i < 8; ++i) {
          int row = i * 32 + (tid >> 3), col = (tid & 7) * 8;
          *(bh8*)(sB + i * 2048 + tid * 8) = *(const bh8*)(Bq + (long)row * 1024 + k0 + col);
        }
        __syncthreads();
#pragma unroll
        for (int kc = 0; kc < 64; kc += 32) {
          bh8 av = *(bh8*)(sA + am * 64 + kc + ak);
#pragma unroll
          for (int j = 0; j < 4; ++j) {
            bh8 bv = *(bh8*)(sB + (w * 64 + j * 16 + am) * 64 + kc + ak);
            acc[j] = __builtin_amdgcn_mfma_f32_16x16x32_bf16(av, bv, acc[j], 0, 0, 0);
          }
        }
      }
      __syncthreads();
      float* sq = (float*)sm;  // [16][256], reuses dead staging LDS
      const long ob = (long)t * 512 * 1536;
#pragma unroll
      for (int j = 0; j < 4; ++j)
#pragma unroll
        for (int r = 0; r < 4; ++r) {
          int row = dr + r;
          int col = w * 64 + j * 16 + dc;
          int b = m0 + row;
          float v = acc[j][r] + bias[col];
          float o = (col < 128) ? v : (softplus_f(v) + 0.1f);
          a.out[ob + (long)b * 1536 + (isQ ? 256 : 0) + col] = o;
          if (isQ) sq[row * 256 + col] = o;
        }
      if (isQ && t + 1 < 64) {
        __syncthreads();
        for (int it = tid; it < 2048; it += THREADS) {
          int row = it >> 7, j = it & 127, b = m0 + row;
          float stoc = sq[row * 256 + j] + sq[row * 256 + 128 + j] * a.noise[((long)t * 512 + b) * 128 + j];
          a.xin[(long)b * 192 + j] = f2b(stoc * a.nont[(t + 1) * 512 + b]);
        }
        {
          int row = tid >> 4, ja = tid & 15, b = m0 + row;
          a.xin[(long)b * 192 + 128 + ja] = f2b(a.actions[((long)(t + 1) * 512 + b) * 16 + ja]);
        }
      }
    }
    round += GRID_BLOCKS; gbar(a.bar, round);
  }
}

extern "C" void kernel_launch(void* const* d_in, const int* in_sizes, int n_in,
                              void* d_out, int out_size, void* d_ws, size_t ws_size,
                              hipStream_t stream) {
  RArgs a;
  a.actions    = (const float*)d_in[0];
  a.nont       = (const float*)d_in[1];
  a.obs        = (const float*)d_in[2];
  a.noise      = (const float*)d_in[3];
  a.init_stoc  = (const float*)d_in[4];
  a.init_deter = (const float*)d_in[5];
  a.W_in = (const float*)d_in[6];  a.b_in = (const float*)d_in[7];
  a.W_ih = (const float*)d_in[8];  a.W_hh = (const float*)d_in[9];
  a.b_ih = (const float*)d_in[10]; a.b_hh = (const float*)d_in[11];
  a.Wp1 = (const float*)d_in[12];  a.bp1 = (const float*)d_in[13];
  a.Wp2 = (const float*)d_in[14];  a.bp2 = (const float*)d_in[15];
  a.Wq1 = (const float*)d_in[16];  a.bq1 = (const float*)d_in[17];
  a.Wq2 = (const float*)d_in[18];  a.bq2 = (const float*)d_in[19];
  a.out = (float*)d_out;

  char* p = (char*)d_ws;
  auto alloc = [&](size_t bytes) { char* r = p; p += (bytes + 255) & ~(size_t)255; return r; };
  a.bar     = (int*)alloc(256);
  a.Wi_b    = (u16*)alloc(1024 * 192 * 2);
  a.Wih_b   = (u16*)alloc((size_t)3072 * 1024 * 2);
  a.Whh_b   = (u16*)alloc((size_t)3072 * 1024 * 2);
  a.Wp1_b   = (u16*)alloc((size_t)1024 * 1024 * 2);
  a.Wp2_b   = (u16*)alloc((size_t)256 * 1024 * 2);
  a.Wq1_b   = (u16*)alloc((size_t)1024 * 2048 * 2);
  a.Wq2_b   = (u16*)alloc((size_t)256 * 1024 * 2);
  a.xin     = (u16*)alloc((size_t)512 * 192 * 2);
  a.x_b     = (u16*)alloc((size_t)512 * 1024 * 2);
  a.hprev_b = (u16*)alloc((size_t)512 * 1024 * 2);
  a.hb      = (u16*)alloc((size_t)512 * 1024 * 2);
  a.obs_cur = (u16*)alloc((size_t)512 * 1024 * 2);
  a.g1      = (u16*)alloc((size_t)512 * 1024 * 2);
  a.q1e     = (u16*)alloc((size_t)512 * 1024 * 2);
  a.h32     = (float*)alloc((size_t)512 * 1024 * 4);
  a.gg      = (float*)alloc((size_t)512 * 6144 * 4);

  hipMemsetAsync(a.bar, 0, 256, stream);
  rssm_kernel<<<dim3(GRID_BLOCKS), dim3(THREADS), 0, stream>>>(a);
}